// Round 5
// baseline (190.787 us; speedup 1.0000x reference)
//
#include <hip/hip_runtime.h>
#include <math.h>

// Problem constants (fixed by reference)
constexpr int Bn = 4, Ln = 2048, DM = 512, NH = 8, DKv = 32, INNER = 256;
constexpr int TTOK = Bn * Ln;                              // 8192 tokens
constexpr size_t HEAD_ELEMS = (size_t)Bn * NH * Ln * DKv;  // 2,097,152 elems per Q/K/V

// Workspace layout (shorts):
//  [0,2M)   Qh bf16 [n,h,l,d]  (PRE-SCALED by log2(e)/sqrt(32))
//  [2M,4M)  Kh bf16 [n,h,l,d]
//  [4M,6M)  Vt bf16 [n,h,d,l]
//  [6M,8M)  O2b bf16 [tok][256]
//  [WFCB_OFF, +131072) Wfcb bf16  (converted by proj's mat==0 blocks)

typedef short short8 __attribute__((ext_vector_type(8)));   // 8 bf16 (4 VGPRs)
typedef short short4v __attribute__((ext_vector_type(4)));  // 4 bf16 (2 VGPRs)
typedef float floatx4 __attribute__((ext_vector_type(4)));  // 16x16 MFMA C/D frag
typedef float floatx16 __attribute__((ext_vector_type(16))); // 32x32 MFMA C/D frag

constexpr size_t WFCB_OFF = 12930048;               // shorts, 16B aligned

constexpr float C1 = 0.25505654f;  // log2(e)/sqrt(32), folded into Qh at projection

__device__ inline short f2bf(float x) {                     // RNE f32->bf16
  unsigned u = __builtin_bit_cast(unsigned, x);
  unsigned r = (u + 0x7FFFu + ((u >> 16) & 1u)) >> 16;
  return (short)r;
}

// ---------------- Projection (bf16 MFMA): X read once, W converted in-reg ----------------
// grid (TTOK/64, 3), block 256 = 4 waves. Block = 64 tokens x ALL 256 cols.
// W is staged straight from FP32 global with in-register f2bf during the prefetch
// (removes the cvtw kernel + its launch gap; extra L2 bytes overlap MFMA).
// Wfc bf16 conversion is a side-task of the 128 mat==0 blocks (4 elems/thread,
// exact cover) -- done long before fcln launches.
// Internal col j = h*32+d, physical W row = (j&31)*8+(j>>5). BK=64 chunks,
// reg prefetch, 2 barriers/chunk. Epilogue: LDS transpose (pitch 268 Q/K, 72 V),
// 16B/lane coalesced stores.
__global__ __launch_bounds__(256) void proj_kernel(
    const float* __restrict__ q, const float* __restrict__ k, const float* __restrict__ v,
    const float* __restrict__ Wqf, const float* __restrict__ Wkf,
    const float* __restrict__ Wvf, const float* __restrict__ Wfc,
    const float* __restrict__ bq, const float* __restrict__ bk,
    const float* __restrict__ bv,
    short* __restrict__ ws, short* __restrict__ Wfcb)
{
  const int mat = blockIdx.y;
  const float* X    = mat == 0 ? q   : (mat == 1 ? k   : v);
  const float* Wf   = mat == 0 ? Wqf : (mat == 1 ? Wkf : Wvf);
  const float* bias = mat == 0 ? bq  : (mat == 1 ? bk  : bv);
  short* outp = ws + (size_t)mat * HEAD_ELEMS;

  const int t0 = blockIdx.x * 64;
  const int tid = threadIdx.x;
  const int col = tid & 15;
  const int quad = (tid & 63) >> 4;
  const int w = tid >> 6;

  // side-task: Wfc fp32 -> bf16 (128 blocks x 256 threads x 4 elems = 131072)
  if (mat == 0) {
    const int idx = (blockIdx.x * 256 + tid) * 4;
    float4 x = *(const float4*)&Wfc[idx];
    *(short4v*)&Wfcb[idx] = (short4v){f2bf(x.x), f2bf(x.y), f2bf(x.z), f2bf(x.w)};
  }

  __shared__ short smem[23040];           // 46.1 KB: Xs[64*72] | Wsh[256*72]
  short* Xs  = smem;
  short* Wsh = smem + 64 * 72;

  floatx4 acc[16];
#pragma unroll
  for (int nj = 0; nj < 16; ++nj) acc[nj] = (floatx4){0.f, 0.f, 0.f, 0.f};

  float4 xr[4];
  short8 wr[8];
  auto loadX = [&](int k0) {
#pragma unroll
    for (int j = 0; j < 4; ++j) {
      const int i = tid + j * 256, row = i >> 4, c4 = i & 15;
      xr[j] = *(const float4*)&X[(size_t)(t0 + row) * DM + k0 + c4 * 4];
    }
  };
  auto loadW = [&](int k0) {                 // fp32 load + in-reg bf16 convert
#pragma unroll
    for (int j = 0; j < 8; ++j) {
      const int s = tid + j * 256, jrow = s >> 3, c8 = s & 7;
      const int wrow = ((jrow & 31) << 3) + (jrow >> 5);   // internal j -> W row
      float4 a = *(const float4*)&Wf[(size_t)wrow * DM + k0 + c8 * 8];
      float4 b = *(const float4*)&Wf[(size_t)wrow * DM + k0 + c8 * 8 + 4];
      wr[j] = (short8){f2bf(a.x), f2bf(a.y), f2bf(a.z), f2bf(a.w),
                       f2bf(b.x), f2bf(b.y), f2bf(b.z), f2bf(b.w)};
    }
  };

  loadX(0);
  loadW(0);

  for (int kc = 0; kc < 8; ++kc) {
#pragma unroll
    for (int j = 0; j < 4; ++j) {
      const int i = tid + j * 256, row = i >> 4, c4 = i & 15;
      *(short4v*)&Xs[row * 72 + c4 * 4] =
          (short4v){f2bf(xr[j].x), f2bf(xr[j].y), f2bf(xr[j].z), f2bf(xr[j].w)};
    }
#pragma unroll
    for (int j = 0; j < 8; ++j) {
      const int s = tid + j * 256, jrow = s >> 3, c8 = s & 7;
      *(short8*)&Wsh[jrow * 72 + c8 * 8] = wr[j];
    }
    __syncthreads();
    if (kc < 7) {                       // prefetch next chunk while MFMAs run
      loadX((kc + 1) * 64);
      loadW((kc + 1) * 64);
    }
#pragma unroll
    for (int ks = 0; ks < 2; ++ks) {
      short8 a = *(const short8*)&Xs[(w * 16 + col) * 72 + ks * 32 + quad * 8];
#pragma unroll
      for (int nj = 0; nj < 16; ++nj) {
        short8 b = *(const short8*)&Wsh[(nj * 16 + col) * 72 + ks * 32 + quad * 8];
        acc[nj] = __builtin_amdgcn_mfma_f32_16x16x32_bf16(a, b, acc[nj], 0, 0, 0);
      }
    }
    __syncthreads();
  }

  // ---- epilogue: bias (+C1 for Q), LDS transpose, coalesced 16B stores ----
  short* Ct = smem;
  const int n = t0 >> 11, llb = t0 & (Ln - 1);

  if (mat < 2) {
    // Ct[t][j], pitch 268 (134 dwords == 6 mod 32: write phase conflict-free)
#pragma unroll
    for (int nj = 0; nj < 16; ++nj) {
      const int j = nj * 16 + col;
      const int c = ((j & 31) << 3) + (j >> 5);
      const float bi = bias[c];
#pragma unroll
      for (int r = 0; r < 4; ++r) {
        float pv = acc[nj][r] + bi;
        if (mat == 0) pv *= C1;
        Ct[(w * 16 + quad * 4 + r) * 268 + j] = f2bf(pv);
      }
    }
    __syncthreads();
    // 2048 chunks: id = h*256 + tok*4 + o ; per head a 4KB contiguous run
#pragma unroll
    for (int it = 0; it < 8; ++it) {
      const int cid = tid + it * 256;
      const int h = cid >> 8, tok = (cid >> 2) & 63, o = cid & 3;
      short8 val = *(const short8*)&Ct[tok * 268 + h * 32 + o * 8];
      *(short8*)&outp[((size_t)(n * NH + h) * Ln + llb + tok) * DKv + o * 8] = val;
    }
  } else {
    // CtV[j][t], pitch 72 (lane's 4 r-values are consecutive tokens -> b64 write)
#pragma unroll
    for (int nj = 0; nj < 16; ++nj) {
      const int j = nj * 16 + col;
      const int c = ((j & 31) << 3) + (j >> 5);
      const float bi = bias[c];
      short4v pk = (short4v){f2bf(acc[nj][0] + bi), f2bf(acc[nj][1] + bi),
                             f2bf(acc[nj][2] + bi), f2bf(acc[nj][3] + bi)};
      *(short4v*)&Ct[j * 72 + w * 16 + quad * 4] = pk;
    }
    __syncthreads();
    // 2048 chunks: id = j*8 + to ; per (h,d): full 128B output line
#pragma unroll
    for (int it = 0; it < 8; ++it) {
      const int cid = tid + it * 256;
      const int j = cid >> 3, to = cid & 7;
      const int h = j >> 5, d = j & 31;
      short8 val = *(const short8*)&Ct[j * 72 + to * 8];
      *(short8*)&outp[((size_t)(n * NH + h) * DKv + d) * Ln + llb + to * 8] = val;
    }
  }
}

// ---------------- Attention: 32x32 MFMA register-P flash ----------------
// grid (Ln/128, Bn*NH) remapped so each head's 16 q-blocks share vid%8 -> one XCD
// owns each head and its 256KB K/V panel stays L2-resident (4 heads = 1MB/XCD).
// block 256 = 4 waves, 32 q per wave (q = lane&31).
// St (32key x 32q) = K·Q^T via 2x mfma_32x32x16; K staged with bit2<->bit3 key
// permutation per 32-group so St C-regs 0..7 / 8..15 are exactly the B-frags of the
// PV MFMAs. P stays in registers; O^T = V^T·P and l = ones^T·P via mfma_32x32x16.
// 128-key chunks, LDS double-buffered, one barrier per chunk.
__global__ __launch_bounds__(256) void attn_kernel(const short* __restrict__ ws,
                                                   short* __restrict__ O2b)
{
  // bijective XCD swizzle: vid%8 == xcd; head = xcd*4 + (vid>>3)>>4
  const int vid = blockIdx.x + 16 * blockIdx.y;
  const int xcd = vid & 7, jj = vid >> 3;
  const int bh = xcd * 4 + (jj >> 4);
  const int qblk = jj & 15;

  const int n = bh >> 3, h = bh & 7;
  const int tid = threadIdx.x;
  const int lane = tid & 63;
  const int col = lane & 31;        // q (and m) index
  const int hf = lane >> 5;         // lane half: k-slot group
  const int w = tid >> 6;
  const int qi = qblk * 128 + w * 32 + col;   // this lane's q row

  const short* Qh = ws;
  const short* Kg = ws + HEAD_ELEMS + (size_t)bh * Ln * DKv;      // [l][d]
  const short* Vg = ws + 2 * HEAD_ELEMS + (size_t)bh * DKv * Ln;  // [d][l]

  __shared__ short Ks[2][128 * 40];   // [perm key][d], pitch 40
  __shared__ short Vs[2][32 * 136];   // [d][key natural], pitch 136

  // Q as B-frags (pre-scaled by C1): B[k=d=c*16+8*hf+j][n=q=col]
  short8 aq[2];
#pragma unroll
  for (int c = 0; c < 2; ++c)
    aq[c] = *(const short8*)&Qh[(size_t)bh * Ln * DKv + (size_t)qi * DKv + c * 16 + hf * 8];

  short8 ones;
#pragma unroll
  for (int j = 0; j < 8; ++j) ones[j] = (short)0x3F80;  // bf16 1.0

  floatx16 o, ol;
#pragma unroll
  for (int i = 0; i < 16; ++i) { o[i] = 0.f; ol[i] = 0.f; }

  // K staging: thread (kg,khalf); LDS row = kg with bits 2,3 swapped (32-group perm)
  const int kg = tid >> 1, khalf = tid & 1;
  const int krow = (kg & ~12) | ((kg & 4) << 1) | ((kg & 8) >> 1);
  const int kst = krow * 40 + khalf * 16;
  // V staging: thread (vd, vkb) -> natural order
  const int vd = tid >> 3, vkb = tid & 7;
  const int vst = vd * 136 + vkb * 16;

  short8 kr0 = *(const short8*)(Kg + kg * 32 + khalf * 16);
  short8 kr1 = *(const short8*)(Kg + kg * 32 + khalf * 16 + 8);
  short8 vr0 = *(const short8*)(Vg + (size_t)vd * Ln + vkb * 16);
  short8 vr1 = *(const short8*)(Vg + (size_t)vd * Ln + vkb * 16 + 8);

  for (int kt = 0; kt < 16; ++kt) {
    short* ksb = Ks[kt & 1];
    short* vsb = Vs[kt & 1];
    *(short8*)&ksb[kst] = kr0;
    *(short8*)&ksb[kst + 8] = kr1;
    *(short8*)&vsb[vst] = vr0;
    *(short8*)&vsb[vst + 8] = vr1;
    __syncthreads();
    if (kt < 15) {                      // register prefetch of next 128-key chunk
      kr0 = *(const short8*)(Kg + (size_t)(kt + 1) * 4096 + kg * 32 + khalf * 16);
      kr1 = *(const short8*)(Kg + (size_t)(kt + 1) * 4096 + kg * 32 + khalf * 16 + 8);
      vr0 = *(const short8*)(Vg + (size_t)vd * Ln + (kt + 1) * 128 + vkb * 16);
      vr1 = *(const short8*)(Vg + (size_t)vd * Ln + (kt + 1) * 128 + vkb * 16 + 8);
    }

#pragma unroll
    for (int cc = 0; cc < 4; ++cc) {    // 32-key sub-chunks
      // St = K·Q^T  (A rows = permuted-key LDS rows; contraction over d=32)
      floatx16 st;
#pragma unroll
      for (int i = 0; i < 16; ++i) st[i] = 0.f;
      short8 kf0 = *(const short8*)&ksb[(cc * 32 + col) * 40 + hf * 8];
      short8 kf1 = *(const short8*)&ksb[(cc * 32 + col) * 40 + 16 + hf * 8];
      st = __builtin_amdgcn_mfma_f32_32x32x16_bf16(kf0, aq[0], st, 0, 0, 0);
      st = __builtin_amdgcn_mfma_f32_32x32x16_bf16(kf1, aq[1], st, 0, 0, 0);

      // p = exp2(st) (already log2-scaled); pack regs 0..7 / 8..15 -> B-frags
      float p[16];
#pragma unroll
      for (int i = 0; i < 16; ++i) p[i] = __builtin_amdgcn_exp2f(st[i]);
      short8 pf[2];
#pragma unroll
      for (int half = 0; half < 2; ++half) {
        unsigned u0 = __builtin_amdgcn_perm(
            __builtin_bit_cast(unsigned, p[half * 8 + 1]),
            __builtin_bit_cast(unsigned, p[half * 8 + 0]), 0x07060302u);
        unsigned u1 = __builtin_amdgcn_perm(
            __builtin_bit_cast(unsigned, p[half * 8 + 3]),
            __builtin_bit_cast(unsigned, p[half * 8 + 2]), 0x07060302u);
        unsigned u2 = __builtin_amdgcn_perm(
            __builtin_bit_cast(unsigned, p[half * 8 + 5]),
            __builtin_bit_cast(unsigned, p[half * 8 + 4]), 0x07060302u);
        unsigned u3 = __builtin_amdgcn_perm(
            __builtin_bit_cast(unsigned, p[half * 8 + 7]),
            __builtin_bit_cast(unsigned, p[half * 8 + 6]), 0x07060302u);
        uint4 uu = make_uint4(u0, u1, u2, u3);
        pf[half] = __builtin_bit_cast(short8, uu);
      }

      // l += ones^T · P   (all D rows identical = row-sum per q)
      ol = __builtin_amdgcn_mfma_f32_32x32x16_bf16(ones, pf[0], ol, 0, 0, 0);
      ol = __builtin_amdgcn_mfma_f32_32x32x16_bf16(ones, pf[1], ol, 0, 0, 0);

      // O^T += V^T · P  (A = V natural order: keys cc*32 + 16*half + 8*hf + j)
      short8 va0 = *(const short8*)&vsb[col * 136 + cc * 32 + hf * 8];
      short8 va1 = *(const short8*)&vsb[col * 136 + cc * 32 + 16 + hf * 8];
      o = __builtin_amdgcn_mfma_f32_32x32x16_bf16(va0, pf[0], o, 0, 0, 0);
      o = __builtin_amdgcn_mfma_f32_32x32x16_bf16(va1, pf[1], o, 0, 0, 0);
    }
  }

  // epilogue: l = any ol reg (rows identical); normalize; write O^T
  const float inv = 1.f / ol[0];
  short* dst = &O2b[((size_t)n * Ln + qi) * INNER + h * DKv];
#pragma unroll
  for (int g4 = 0; g4 < 4; ++g4) {      // regs 4g4..4g4+3 -> d = 8*g4 + 4*hf + (0..3)
    short4v pk = (short4v){f2bf(o[g4 * 4 + 0] * inv), f2bf(o[g4 * 4 + 1] * inv),
                           f2bf(o[g4 * 4 + 2] * inv), f2bf(o[g4 * 4 + 3] * inv)};
    *(short4v*)&dst[8 * g4 + 4 * hf] = pk;
  }
}

// ---------------- Fused FC + residual + LayerNorm -> fp32 out ----------------
// grid (TTOK/16), block 256 = 4 waves. Block = 16 tokens x 512 cols; wave w owns
// cols [w*128, w*128+128). A (O2b) staged in LDS; W read as B-frags straight from
// global (Wfcb = 256KB, fully L2-resident -- don't stage what caches fit).
// x = fc + bias + resid kept in FP32 registers (no bf16 round-trip), per-token
// mean/var via shfl_xor within 16-lane groups + tiny cross-wave LDS reduce.
__global__ __launch_bounds__(256) void fcln_kernel(
    const short* __restrict__ O2b, const short* __restrict__ Wfcb,
    const float* __restrict__ bfc, const float* __restrict__ qin,
    const float* __restrict__ gamma, const float* __restrict__ beta,
    float* __restrict__ outp)
{
  const int t0 = blockIdx.x * 16;
  const int tid = threadIdx.x;
  const int col = tid & 15;
  const int quad = (tid & 63) >> 4;
  const int w = tid >> 6;

  __shared__ short As[16 * 264];
  __shared__ float sred[2][16][4];

  {
    const int row = tid >> 4, k16 = tid & 15;        // 16 rows x 16 shorts/thread
    *(short8*)&As[row * 264 + k16 * 16] =
        *(const short8*)&O2b[(size_t)(t0 + row) * INNER + k16 * 16];
    *(short8*)&As[row * 264 + k16 * 16 + 8] =
        *(const short8*)&O2b[(size_t)(t0 + row) * INNER + k16 * 16 + 8];
  }
  __syncthreads();

  const short* Wp = Wfcb + (size_t)(w * 128 + col) * INNER + quad * 8;

  floatx4 acc[8];
#pragma unroll
  for (int nj = 0; nj < 8; ++nj) acc[nj] = (floatx4){0.f, 0.f, 0.f, 0.f};

#pragma unroll
  for (int ks = 0; ks < 8; ++ks) {
    short8 a = *(const short8*)&As[col * 264 + ks * 32 + quad * 8];
#pragma unroll
    for (int nj = 0; nj < 8; ++nj) {
      short8 b = *(const short8*)&Wp[(size_t)nj * 16 * INNER + ks * 32];
      acc[nj] = __builtin_amdgcn_mfma_f32_16x16x32_bf16(a, b, acc[nj], 0, 0, 0);
    }
  }

  // x = acc + bias + residual (fp32), accumulate per-token partial sums
  float s1[4], s2[4];
#pragma unroll
  for (int r = 0; r < 4; ++r) { s1[r] = 0.f; s2[r] = 0.f; }

#pragma unroll
  for (int nj = 0; nj < 8; ++nj) {
    const int c = w * 128 + nj * 16 + col;
    const float bi = bfc[c];
#pragma unroll
    for (int r = 0; r < 4; ++r) {
      const int t = t0 + quad * 4 + r;
      float x = acc[nj][r] + bi + qin[(size_t)t * DM + c];
      acc[nj][r] = x;
      s1[r] += x;
      s2[r] += x * x;
    }
  }
  // reduce across the 16 lanes of this quad group (cols of this wave)
#pragma unroll
  for (int r = 0; r < 4; ++r) {
#pragma unroll
    for (int off = 1; off <= 8; off <<= 1) {
      s1[r] += __shfl_xor(s1[r], off);
      s2[r] += __shfl_xor(s2[r], off);
    }
  }
  if (col == 0) {
#pragma unroll
    for (int r = 0; r < 4; ++r) {
      sred[0][quad * 4 + r][w] = s1[r];
      sred[1][quad * 4 + r][w] = s2[r];
    }
  }
  __syncthreads();

  float mean[4], rstd[4];
#pragma unroll
  for (int r = 0; r < 4; ++r) {
    const int tk = quad * 4 + r;
    const float S1 = sred[0][tk][0] + sred[0][tk][1] + sred[0][tk][2] + sred[0][tk][3];
    const float S2 = sred[1][tk][0] + sred[1][tk][1] + sred[1][tk][2] + sred[1][tk][3];
    mean[r] = S1 * (1.f / 512.f);
    const float var = S2 * (1.f / 512.f) - mean[r] * mean[r];
    rstd[r] = rsqrtf(var + 1e-5f);
  }

#pragma unroll
  for (int nj = 0; nj < 8; ++nj) {
    const int c = w * 128 + nj * 16 + col;
    const float g = gamma[c], bb = beta[c];
#pragma unroll
    for (int r = 0; r < 4; ++r) {
      const int t = t0 + quad * 4 + r;
      outp[(size_t)t * DM + c] = g * (acc[nj][r] - mean[r]) * rstd[r] + bb;
    }
  }
}

extern "C" void kernel_launch(void* const* d_in, const int* in_sizes, int n_in,
                              void* d_out, int out_size, void* d_ws, size_t ws_size,
                              hipStream_t stream) {
  const float* q     = (const float*)d_in[0];
  const float* k     = (const float*)d_in[1];
  const float* v     = (const float*)d_in[2];
  const float* Wq    = (const float*)d_in[3];
  const float* bq    = (const float*)d_in[4];
  const float* Wk    = (const float*)d_in[5];
  const float* bk    = (const float*)d_in[6];
  const float* Wv    = (const float*)d_in[7];
  const float* bv    = (const float*)d_in[8];
  const float* Wfc   = (const float*)d_in[9];
  const float* bfc   = (const float*)d_in[10];
  const float* gamma = (const float*)d_in[11];
  const float* beta  = (const float*)d_in[12];

  short* wsS  = (short*)d_ws;
  short* O2b  = wsS + 3 * HEAD_ELEMS;
  short* Wfcb = wsS + WFCB_OFF;

  dim3 gp(TTOK / 64, 3);
  proj_kernel<<<gp, 256, 0, stream>>>(q, k, v, Wq, Wk, Wv, Wfc, bq, bk, bv,
                                      wsS, Wfcb);

  dim3 gatt(Ln / 128, Bn * NH);
  attn_kernel<<<gatt, 256, 0, stream>>>(wsS, O2b);

  fcln_kernel<<<dim3(TTOK / 16), 256, 0, stream>>>(O2b, Wfcb, bfc, q, gamma, beta,
                                                   (float*)d_out);
}

// Round 6
// 181.891 us; speedup vs baseline: 1.0489x; 1.0489x over previous
//
#include <hip/hip_runtime.h>
#include <math.h>

// Problem constants (fixed by reference)
constexpr int Bn = 4, Ln = 2048, DM = 512, NH = 8, DKv = 32, INNER = 256;
constexpr int TTOK = Bn * Ln;                              // 8192 tokens
constexpr size_t HEAD_ELEMS = (size_t)Bn * NH * Ln * DKv;  // 2,097,152 elems per Q/K/V

// Workspace layout (shorts):
//  [0,2M)   Qh bf16 [n,h,l,d]  (PRE-SCALED by log2(e)/sqrt(32))
//  [2M,4M)  Kh bf16 [n,h,l,d]
//  [4M,6M)  Vt bf16 [n,h,d,l]
//  [6M,8M)  O2b bf16 [tok][256]
//  [12.25M, +393216)  Wb bf16 (Wq|Wk|Wv)
//  [+131072]          Wfcb bf16

typedef short short8 __attribute__((ext_vector_type(8)));   // 8 bf16 (4 VGPRs)
typedef short short4v __attribute__((ext_vector_type(4)));  // 4 bf16 (2 VGPRs)
typedef float floatx4 __attribute__((ext_vector_type(4)));  // 16x16 MFMA C/D frag
typedef float floatx16 __attribute__((ext_vector_type(16))); // 32x32 MFMA C/D frag

constexpr size_t WB_OFF  = 12536832;                // shorts, 16B aligned
constexpr size_t WFCB_OFF = WB_OFF + 3 * 131072;

constexpr float C1 = 0.25505654f;  // log2(e)/sqrt(32), folded into Qh at projection

__device__ inline short f2bf(float x) {                     // RNE f32->bf16
  unsigned u = __builtin_bit_cast(unsigned, x);
  unsigned r = (u + 0x7FFFu + ((u >> 16) & 1u)) >> 16;
  return (short)r;
}

// ---------------- Weight pre-convert: fp32 -> bf16 ----------------
__global__ __launch_bounds__(256) void cvtw_kernel(
    const float* __restrict__ Wq, const float* __restrict__ Wk,
    const float* __restrict__ Wv, const float* __restrict__ Wfc,
    short* __restrict__ Wb, short* __restrict__ Wfcb)
{
  const int z = blockIdx.y;
  const float* src = z == 0 ? Wq : (z == 1 ? Wk : (z == 2 ? Wv : Wfc));
  short* dst = z < 3 ? Wb + (size_t)z * 131072 : Wfcb;
  const int idx = (blockIdx.x * 256 + threadIdx.x) * 4;   // 131072 elems, grid.x=128
  float4 x = *(const float4*)&src[idx];
  *(short4v*)&dst[idx] = (short4v){f2bf(x.x), f2bf(x.y), f2bf(x.z), f2bf(x.w)};
}

// ---------------- Projection (bf16 MFMA), DRAIN-OVERLAP tiled ----------------
// grid (TTOK/64, 4, 3) = 1536 blocks, block 256 = 4 waves, LDS 18.4 KB ->
// 6 blocks/CU RESIDENT (24 waves/CU). Theory (R5 counters: proj 51us, all pipes
// <11%, occupancy 15%): hipcc drains vmcnt(0) at every barrier, exposing the
// ~900cy HBM prefetch each kc; co-resident blocks at staggered kc phases are the
// only cover for that drain (in-block pipelining is defeated by the compiler --
// guide m99-m141). Every prior variant ran <=3 blocks/CU (46-70KB LDS).
// Block = 64 tokens x 64 cols (head pair 2*cp, 2*cp+1). Internal col j:
// h = 2*cp + (j>>5), d = j&31, physical W row = (j&31)*8 + 2*cp + (j>>5).
// BK=64, 8 kc, reg prefetch. Epilogue = R1's proven LDS-transpose + 16B stores.
__global__ __launch_bounds__(256) void proj_kernel(
    const float* __restrict__ q, const float* __restrict__ k, const float* __restrict__ v,
    const short* __restrict__ Wb,
    const float* __restrict__ bq, const float* __restrict__ bk,
    const float* __restrict__ bv,
    short* __restrict__ ws)
{
  const int mat = blockIdx.z;
  const int cp  = blockIdx.y;               // heads 2cp, 2cp+1
  const float* X    = mat == 0 ? q  : (mat == 1 ? k  : v);
  const short* W    = Wb + (size_t)mat * 131072;
  const float* bias = mat == 0 ? bq : (mat == 1 ? bk : bv);
  short* outp = ws + (size_t)mat * HEAD_ELEMS;

  const int t0 = blockIdx.x * 64;
  const int tid = threadIdx.x;
  const int col = tid & 15;
  const int quad = (tid & 63) >> 4;
  const int w = tid >> 6;

  __shared__ short smem[9216];             // 18.4 KB: Xs[64*72] | Wsh[64*72]
  short* Xs  = smem;
  short* Wsh = smem + 64 * 72;

  floatx4 acc[4];
#pragma unroll
  for (int nj = 0; nj < 4; ++nj) acc[nj] = (floatx4){0.f, 0.f, 0.f, 0.f};

  float4 xr[4];
  short8 wr[2];
  auto loadX = [&](int k0) {
#pragma unroll
    for (int j = 0; j < 4; ++j) {
      const int i = tid + j * 256, row = i >> 4, c4 = i & 15;
      xr[j] = *(const float4*)&X[(size_t)(t0 + row) * DM + k0 + c4 * 4];
    }
  };
  auto loadW = [&](int k0) {
#pragma unroll
    for (int j = 0; j < 2; ++j) {
      const int s = tid + j * 256, jrow = s >> 3, c8 = s & 7;
      const int wrow = ((jrow & 31) << 3) + 2 * cp + (jrow >> 5);
      wr[j] = *(const short8*)&W[(size_t)wrow * DM + k0 + c8 * 8];
    }
  };

  loadX(0);
  loadW(0);

  for (int kc = 0; kc < 8; ++kc) {
#pragma unroll
    for (int j = 0; j < 4; ++j) {
      const int i = tid + j * 256, row = i >> 4, c4 = i & 15;
      *(short4v*)&Xs[row * 72 + c4 * 4] =
          (short4v){f2bf(xr[j].x), f2bf(xr[j].y), f2bf(xr[j].z), f2bf(xr[j].w)};
    }
#pragma unroll
    for (int j = 0; j < 2; ++j) {
      const int s = tid + j * 256, jrow = s >> 3, c8 = s & 7;
      *(short8*)&Wsh[jrow * 72 + c8 * 8] = wr[j];
    }
    __syncthreads();
    if (kc < 7) {                       // prefetch next chunk while MFMAs run
      loadX((kc + 1) * 64);
      loadW((kc + 1) * 64);
    }
#pragma unroll
    for (int ks = 0; ks < 2; ++ks) {
      short8 a = *(const short8*)&Xs[(w * 16 + col) * 72 + ks * 32 + quad * 8];
#pragma unroll
      for (int nj = 0; nj < 4; ++nj) {
        short8 b = *(const short8*)&Wsh[(nj * 16 + col) * 72 + ks * 32 + quad * 8];
        acc[nj] = __builtin_amdgcn_mfma_f32_16x16x32_bf16(a, b, acc[nj], 0, 0, 0);
      }
    }
    __syncthreads();
  }

  // ---- epilogue: bias (+C1 for Q), LDS transpose, coalesced 16B stores ----
  short* Ct = smem;
  const int n = t0 >> 11, llb = t0 & (Ln - 1);

  if (mat < 2) {
    // Ct[t][j], pitch 72
#pragma unroll
    for (int nj = 0; nj < 4; ++nj) {
      const int j = nj * 16 + col;
      const int c = ((j & 31) << 3) + 2 * cp + (j >> 5);
      const float bi = bias[c];
#pragma unroll
      for (int r = 0; r < 4; ++r) {
        float pv = acc[nj][r] + bi;
        if (mat == 0) pv *= C1;
        Ct[(w * 16 + quad * 4 + r) * 72 + j] = f2bf(pv);
      }
    }
    __syncthreads();
    // 512 chunks: id = h_loc*256 + tok*4 + o ; per h_loc a contiguous 8KB run
#pragma unroll
    for (int it = 0; it < 2; ++it) {
      const int cid = tid + it * 256;
      const int h_loc = cid >> 8, tok = (cid >> 2) & 63, o = cid & 3;
      short8 val = *(const short8*)&Ct[tok * 72 + h_loc * 32 + o * 8];
      const int h = 2 * cp + h_loc;
      *(short8*)&outp[((size_t)(n * NH + h) * Ln + llb + tok) * DKv + o * 8] = val;
    }
  } else {
    // CtV[j][t], pitch 72 (lane's 4 r-values are consecutive tokens -> b64 write)
#pragma unroll
    for (int nj = 0; nj < 4; ++nj) {
      const int j = nj * 16 + col;
      const int c = ((j & 31) << 3) + 2 * cp + (j >> 5);
      const float bi = bias[c];
      short4v pk = (short4v){f2bf(acc[nj][0] + bi), f2bf(acc[nj][1] + bi),
                             f2bf(acc[nj][2] + bi), f2bf(acc[nj][3] + bi)};
      *(short4v*)&Ct[j * 72 + w * 16 + quad * 4] = pk;
    }
    __syncthreads();
    // 512 chunks: id = j*8 + to ; per (h,d): full 128B output line
#pragma unroll
    for (int it = 0; it < 2; ++it) {
      const int cid = tid + it * 256;
      const int j = cid >> 3, to = cid & 7;
      const int h = 2 * cp + (j >> 5), d = j & 31;
      short8 val = *(const short8*)&Ct[j * 72 + to * 8];
      *(short8*)&outp[((size_t)(n * NH + h) * DKv + d) * Ln + llb + to * 8] = val;
    }
  }
}

// ---------------- Attention: 32x32 MFMA register-P flash ----------------
// grid (Ln/128, Bn*NH) remapped so each head's 16 q-blocks share vid%8 -> one XCD
// owns each head and its 256KB K/V panel stays L2-resident (4 heads = 1MB/XCD).
// block 256 = 4 waves, 32 q per wave (q = lane&31).
// St (32key x 32q) = K·Q^T via 2x mfma_32x32x16; K staged with bit2<->bit3 key
// permutation per 32-group so St C-regs 0..7 / 8..15 are exactly the B-frags of the
// PV MFMAs. P stays in registers; O^T = V^T·P and l = ones^T·P via mfma_32x32x16.
// 128-key chunks, LDS double-buffered, one barrier per chunk.
__global__ __launch_bounds__(256) void attn_kernel(const short* __restrict__ ws,
                                                   short* __restrict__ O2b)
{
  // bijective XCD swizzle: vid%8 == xcd; head = xcd*4 + (vid>>3)>>4
  const int vid = blockIdx.x + 16 * blockIdx.y;
  const int xcd = vid & 7, jj = vid >> 3;
  const int bh = xcd * 4 + (jj >> 4);
  const int qblk = jj & 15;

  const int n = bh >> 3, h = bh & 7;
  const int tid = threadIdx.x;
  const int lane = tid & 63;
  const int col = lane & 31;        // q (and m) index
  const int hf = lane >> 5;         // lane half: k-slot group
  const int w = tid >> 6;
  const int qi = qblk * 128 + w * 32 + col;   // this lane's q row

  const short* Qh = ws;
  const short* Kg = ws + HEAD_ELEMS + (size_t)bh * Ln * DKv;      // [l][d]
  const short* Vg = ws + 2 * HEAD_ELEMS + (size_t)bh * DKv * Ln;  // [d][l]

  __shared__ short Ks[2][128 * 40];   // [perm key][d], pitch 40
  __shared__ short Vs[2][32 * 136];   // [d][key natural], pitch 136

  // Q as B-frags (pre-scaled by C1): B[k=d=c*16+8*hf+j][n=q=col]
  short8 aq[2];
#pragma unroll
  for (int c = 0; c < 2; ++c)
    aq[c] = *(const short8*)&Qh[(size_t)bh * Ln * DKv + (size_t)qi * DKv + c * 16 + hf * 8];

  short8 ones;
#pragma unroll
  for (int j = 0; j < 8; ++j) ones[j] = (short)0x3F80;  // bf16 1.0

  floatx16 o, ol;
#pragma unroll
  for (int i = 0; i < 16; ++i) { o[i] = 0.f; ol[i] = 0.f; }

  // K staging: thread (kg,khalf); LDS row = kg with bits 2,3 swapped (32-group perm)
  const int kg = tid >> 1, khalf = tid & 1;
  const int krow = (kg & ~12) | ((kg & 4) << 1) | ((kg & 8) >> 1);
  const int kst = krow * 40 + khalf * 16;
  // V staging: thread (vd, vkb) -> natural order
  const int vd = tid >> 3, vkb = tid & 7;
  const int vst = vd * 136 + vkb * 16;

  short8 kr0 = *(const short8*)(Kg + kg * 32 + khalf * 16);
  short8 kr1 = *(const short8*)(Kg + kg * 32 + khalf * 16 + 8);
  short8 vr0 = *(const short8*)(Vg + (size_t)vd * Ln + vkb * 16);
  short8 vr1 = *(const short8*)(Vg + (size_t)vd * Ln + vkb * 16 + 8);

  for (int kt = 0; kt < 16; ++kt) {
    short* ksb = Ks[kt & 1];
    short* vsb = Vs[kt & 1];
    *(short8*)&ksb[kst] = kr0;
    *(short8*)&ksb[kst + 8] = kr1;
    *(short8*)&vsb[vst] = vr0;
    *(short8*)&vsb[vst + 8] = vr1;
    __syncthreads();
    if (kt < 15) {                      // register prefetch of next 128-key chunk
      kr0 = *(const short8*)(Kg + (size_t)(kt + 1) * 4096 + kg * 32 + khalf * 16);
      kr1 = *(const short8*)(Kg + (size_t)(kt + 1) * 4096 + kg * 32 + khalf * 16 + 8);
      vr0 = *(const short8*)(Vg + (size_t)vd * Ln + (kt + 1) * 128 + vkb * 16);
      vr1 = *(const short8*)(Vg + (size_t)vd * Ln + (kt + 1) * 128 + vkb * 16 + 8);
    }

#pragma unroll
    for (int cc = 0; cc < 4; ++cc) {    // 32-key sub-chunks
      // St = K·Q^T  (A rows = permuted-key LDS rows; contraction over d=32)
      floatx16 st;
#pragma unroll
      for (int i = 0; i < 16; ++i) st[i] = 0.f;
      short8 kf0 = *(const short8*)&ksb[(cc * 32 + col) * 40 + hf * 8];
      short8 kf1 = *(const short8*)&ksb[(cc * 32 + col) * 40 + 16 + hf * 8];
      st = __builtin_amdgcn_mfma_f32_32x32x16_bf16(kf0, aq[0], st, 0, 0, 0);
      st = __builtin_amdgcn_mfma_f32_32x32x16_bf16(kf1, aq[1], st, 0, 0, 0);

      // p = exp2(st) (already log2-scaled); pack regs 0..7 / 8..15 -> B-frags
      float p[16];
#pragma unroll
      for (int i = 0; i < 16; ++i) p[i] = __builtin_amdgcn_exp2f(st[i]);
      short8 pf[2];
#pragma unroll
      for (int half = 0; half < 2; ++half) {
        unsigned u0 = __builtin_amdgcn_perm(
            __builtin_bit_cast(unsigned, p[half * 8 + 1]),
            __builtin_bit_cast(unsigned, p[half * 8 + 0]), 0x07060302u);
        unsigned u1 = __builtin_amdgcn_perm(
            __builtin_bit_cast(unsigned, p[half * 8 + 3]),
            __builtin_bit_cast(unsigned, p[half * 8 + 2]), 0x07060302u);
        unsigned u2 = __builtin_amdgcn_perm(
            __builtin_bit_cast(unsigned, p[half * 8 + 5]),
            __builtin_bit_cast(unsigned, p[half * 8 + 4]), 0x07060302u);
        unsigned u3 = __builtin_amdgcn_perm(
            __builtin_bit_cast(unsigned, p[half * 8 + 7]),
            __builtin_bit_cast(unsigned, p[half * 8 + 6]), 0x07060302u);
        uint4 uu = make_uint4(u0, u1, u2, u3);
        pf[half] = __builtin_bit_cast(short8, uu);
      }

      // l += ones^T · P   (all D rows identical = row-sum per q)
      ol = __builtin_amdgcn_mfma_f32_32x32x16_bf16(ones, pf[0], ol, 0, 0, 0);
      ol = __builtin_amdgcn_mfma_f32_32x32x16_bf16(ones, pf[1], ol, 0, 0, 0);

      // O^T += V^T · P  (A = V natural order: keys cc*32 + 16*half + 8*hf + j)
      short8 va0 = *(const short8*)&vsb[col * 136 + cc * 32 + hf * 8];
      short8 va1 = *(const short8*)&vsb[col * 136 + cc * 32 + 16 + hf * 8];
      o = __builtin_amdgcn_mfma_f32_32x32x16_bf16(va0, pf[0], o, 0, 0, 0);
      o = __builtin_amdgcn_mfma_f32_32x32x16_bf16(va1, pf[1], o, 0, 0, 0);
    }
  }

  // epilogue: l = any ol reg (rows identical); normalize; write O^T
  const float inv = 1.f / ol[0];
  short* dst = &O2b[((size_t)n * Ln + qi) * INNER + h * DKv];
#pragma unroll
  for (int g4 = 0; g4 < 4; ++g4) {      // regs 4g4..4g4+3 -> d = 8*g4 + 4*hf + (0..3)
    short4v pk = (short4v){f2bf(o[g4 * 4 + 0] * inv), f2bf(o[g4 * 4 + 1] * inv),
                           f2bf(o[g4 * 4 + 2] * inv), f2bf(o[g4 * 4 + 3] * inv)};
    *(short4v*)&dst[8 * g4 + 4 * hf] = pk;
  }
}

// ---------------- Fused FC + residual + LayerNorm -> fp32 out ----------------
// grid (TTOK/16), block 256 = 4 waves. Block = 16 tokens x 512 cols; wave w owns
// cols [w*128, w*128+128). A (O2b) staged in LDS; W read as B-frags straight from
// global (Wfcb = 256KB, fully L2-resident -- don't stage what caches fit).
// x = fc + bias + resid kept in FP32 registers (no bf16 round-trip), per-token
// mean/var via shfl_xor within 16-lane groups + tiny cross-wave LDS reduce.
__global__ __launch_bounds__(256) void fcln_kernel(
    const short* __restrict__ O2b, const short* __restrict__ Wfcb,
    const float* __restrict__ bfc, const float* __restrict__ qin,
    const float* __restrict__ gamma, const float* __restrict__ beta,
    float* __restrict__ outp)
{
  const int t0 = blockIdx.x * 16;
  const int tid = threadIdx.x;
  const int col = tid & 15;
  const int quad = (tid & 63) >> 4;
  const int w = tid >> 6;

  __shared__ short As[16 * 264];
  __shared__ float sred[2][16][4];

  {
    const int row = tid >> 4, k16 = tid & 15;        // 16 rows x 16 shorts/thread
    *(short8*)&As[row * 264 + k16 * 16] =
        *(const short8*)&O2b[(size_t)(t0 + row) * INNER + k16 * 16];
    *(short8*)&As[row * 264 + k16 * 16 + 8] =
        *(const short8*)&O2b[(size_t)(t0 + row) * INNER + k16 * 16 + 8];
  }
  __syncthreads();

  const short* Wp = Wfcb + (size_t)(w * 128 + col) * INNER + quad * 8;

  floatx4 acc[8];
#pragma unroll
  for (int nj = 0; nj < 8; ++nj) acc[nj] = (floatx4){0.f, 0.f, 0.f, 0.f};

#pragma unroll
  for (int ks = 0; ks < 8; ++ks) {
    short8 a = *(const short8*)&As[col * 264 + ks * 32 + quad * 8];
#pragma unroll
    for (int nj = 0; nj < 8; ++nj) {
      short8 b = *(const short8*)&Wp[(size_t)nj * 16 * INNER + ks * 32];
      acc[nj] = __builtin_amdgcn_mfma_f32_16x16x32_bf16(a, b, acc[nj], 0, 0, 0);
    }
  }

  // x = acc + bias + residual (fp32), accumulate per-token partial sums
  float s1[4], s2[4];
#pragma unroll
  for (int r = 0; r < 4; ++r) { s1[r] = 0.f; s2[r] = 0.f; }

#pragma unroll
  for (int nj = 0; nj < 8; ++nj) {
    const int c = w * 128 + nj * 16 + col;
    const float bi = bfc[c];
#pragma unroll
    for (int r = 0; r < 4; ++r) {
      const int t = t0 + quad * 4 + r;
      float x = acc[nj][r] + bi + qin[(size_t)t * DM + c];
      acc[nj][r] = x;
      s1[r] += x;
      s2[r] += x * x;
    }
  }
  // reduce across the 16 lanes of this quad group (cols of this wave)
#pragma unroll
  for (int r = 0; r < 4; ++r) {
#pragma unroll
    for (int off = 1; off <= 8; off <<= 1) {
      s1[r] += __shfl_xor(s1[r], off);
      s2[r] += __shfl_xor(s2[r], off);
    }
  }
  if (col == 0) {
#pragma unroll
    for (int r = 0; r < 4; ++r) {
      sred[0][quad * 4 + r][w] = s1[r];
      sred[1][quad * 4 + r][w] = s2[r];
    }
  }
  __syncthreads();

  float mean[4], rstd[4];
#pragma unroll
  for (int r = 0; r < 4; ++r) {
    const int tk = quad * 4 + r;
    const float S1 = sred[0][tk][0] + sred[0][tk][1] + sred[0][tk][2] + sred[0][tk][3];
    const float S2 = sred[1][tk][0] + sred[1][tk][1] + sred[1][tk][2] + sred[1][tk][3];
    mean[r] = S1 * (1.f / 512.f);
    const float var = S2 * (1.f / 512.f) - mean[r] * mean[r];
    rstd[r] = rsqrtf(var + 1e-5f);
  }

#pragma unroll
  for (int nj = 0; nj < 8; ++nj) {
    const int c = w * 128 + nj * 16 + col;
    const float g = gamma[c], bb = beta[c];
#pragma unroll
    for (int r = 0; r < 4; ++r) {
      const int t = t0 + quad * 4 + r;
      outp[(size_t)t * DM + c] = g * (acc[nj][r] - mean[r]) * rstd[r] + bb;
    }
  }
}

extern "C" void kernel_launch(void* const* d_in, const int* in_sizes, int n_in,
                              void* d_out, int out_size, void* d_ws, size_t ws_size,
                              hipStream_t stream) {
  const float* q     = (const float*)d_in[0];
  const float* k     = (const float*)d_in[1];
  const float* v     = (const float*)d_in[2];
  const float* Wq    = (const float*)d_in[3];
  const float* bq    = (const float*)d_in[4];
  const float* Wk    = (const float*)d_in[5];
  const float* bk    = (const float*)d_in[6];
  const float* Wv    = (const float*)d_in[7];
  const float* bv    = (const float*)d_in[8];
  const float* Wfc   = (const float*)d_in[9];
  const float* bfc   = (const float*)d_in[10];
  const float* gamma = (const float*)d_in[11];
  const float* beta  = (const float*)d_in[12];

  short* wsS  = (short*)d_ws;
  short* O2b  = wsS + 3 * HEAD_ELEMS;
  short* Wb   = wsS + WB_OFF;
  short* Wfcb = wsS + WFCB_OFF;

  cvtw_kernel<<<dim3(128, 4), 256, 0, stream>>>(Wq, Wk, Wv, Wfc, Wb, Wfcb);

  dim3 gp(TTOK / 64, 4, 3);
  proj_kernel<<<gp, 256, 0, stream>>>(q, k, v, Wb, bq, bk, bv, wsS);

  dim3 gatt(Ln / 128, Bn * NH);
  attn_kernel<<<gatt, 256, 0, stream>>>(wsS, O2b);

  fcln_kernel<<<dim3(TTOK / 16), 256, 0, stream>>>(O2b, Wfcb, bfc, q, gamma, beta,
                                                   (float*)d_out);
}

// Round 7
// 171.761 us; speedup vs baseline: 1.1108x; 1.0590x over previous
//
#include <hip/hip_runtime.h>
#include <math.h>

// Problem constants (fixed by reference)
constexpr int Bn = 4, Ln = 2048, DM = 512, NH = 8, DKv = 32, INNER = 256;
constexpr int TTOK = Bn * Ln;                              // 8192 tokens
constexpr size_t HEAD_ELEMS = (size_t)Bn * NH * Ln * DKv;  // 2,097,152 elems per Q/K/V

// Workspace layout (shorts):
//  [0,2M)   Qh bf16 [n,h,l,d]  (PRE-SCALED by log2(e)/sqrt(32))
//  [2M,4M)  Kh bf16 [n,h,l,d]
//  [4M,6M)  Vt bf16 [n,h,d,l]
//  [6M,8M)  O2b bf16 [tok][256]
//  [12.25M, +393216)  Wb bf16 (Wq|Wk|Wv)
//  [+131072]          Wfcb bf16

typedef short short8 __attribute__((ext_vector_type(8)));   // 8 bf16 (4 VGPRs)
typedef short short4v __attribute__((ext_vector_type(4)));  // 4 bf16 (2 VGPRs)
typedef float floatx4 __attribute__((ext_vector_type(4)));  // 16x16 MFMA C/D frag
typedef float floatx16 __attribute__((ext_vector_type(16))); // 32x32 MFMA C/D frag

constexpr size_t WB_OFF  = 12536832;                // shorts, 16B aligned
constexpr size_t WFCB_OFF = WB_OFF + 3 * 131072;

constexpr float C1 = 0.25505654f;  // log2(e)/sqrt(32), folded into Qh at projection

__device__ inline short f2bf(float x) {                     // RNE f32->bf16
  unsigned u = __builtin_bit_cast(unsigned, x);
  unsigned r = (u + 0x7FFFu + ((u >> 16) & 1u)) >> 16;
  return (short)r;
}

// ---------------- Weight pre-convert: fp32 -> bf16 ----------------
__global__ __launch_bounds__(256) void cvtw_kernel(
    const float* __restrict__ Wq, const float* __restrict__ Wk,
    const float* __restrict__ Wv, const float* __restrict__ Wfc,
    short* __restrict__ Wb, short* __restrict__ Wfcb)
{
  const int z = blockIdx.y;
  const float* src = z == 0 ? Wq : (z == 1 ? Wk : (z == 2 ? Wv : Wfc));
  short* dst = z < 3 ? Wb + (size_t)z * 131072 : Wfcb;
  const int idx = (blockIdx.x * 256 + threadIdx.x) * 4;   // 131072 elems, grid.x=128
  float4 x = *(const float4*)&src[idx];
  *(short4v*)&dst[idx] = (short4v){f2bf(x.x), f2bf(x.y), f2bf(x.z), f2bf(x.w)};
}

// ---------------- Projection (bf16 MFMA): X once, 2x2 wave tiling ----------------
// grid (TTOK/64, 3), block 256 = 4 waves. Block = 64 tokens x ALL 256 cols (R2
// base: best measured wall). CHANGE vs R2: wave (wr,wc)=(w>>1,w&1) owns a 32tok x
// 128col sub-tile instead of 16tok x 256col. Per K-slice: 2 A + 8 B ds_reads for
// 16 MFMAs (was 1+16 for 16) -> LDS reads/kc 34->20. LDS reads were ~7:1 vs MFMA
// issue on the inter-barrier critical path (R5/R6 falsified occupancy+traffic
// theories; LDS intensity is the remaining computable term).
// Internal col j = h*32+d, physical W row = (j&31)*8+(j>>5). BK=64, 8 kc, reg
// prefetch, 2 barriers/kc. Epilogue: LDS transpose (pitch 268 Q/K, 72 V),
// 16B/lane coalesced stores -- layouts unchanged from R2.
__global__ __launch_bounds__(256) void proj_kernel(
    const float* __restrict__ q, const float* __restrict__ k, const float* __restrict__ v,
    const short* __restrict__ Wb,
    const float* __restrict__ bq, const float* __restrict__ bk,
    const float* __restrict__ bv,
    short* __restrict__ ws)
{
  const int mat = blockIdx.y;
  const float* X    = mat == 0 ? q  : (mat == 1 ? k  : v);
  const short* W    = Wb + (size_t)mat * 131072;
  const float* bias = mat == 0 ? bq : (mat == 1 ? bk : bv);
  short* outp = ws + (size_t)mat * HEAD_ELEMS;

  const int t0 = blockIdx.x * 64;
  const int tid = threadIdx.x;
  const int col = tid & 15;
  const int quad = (tid & 63) >> 4;
  const int w = tid >> 6;
  const int wr = w >> 1, wc = w & 1;        // 2x2 wave sub-tile

  __shared__ short smem[23040];           // 46.1 KB: Xs[64*72] | Wsh[256*72]
  short* Xs  = smem;
  short* Wsh = smem + 64 * 72;

  floatx4 acc[2][8];
#pragma unroll
  for (int ri = 0; ri < 2; ++ri)
#pragma unroll
    for (int nj = 0; nj < 8; ++nj) acc[ri][nj] = (floatx4){0.f, 0.f, 0.f, 0.f};

  float4 xr[4];
  short8 wrg[8];
  auto loadX = [&](int k0) {
#pragma unroll
    for (int j = 0; j < 4; ++j) {
      const int i = tid + j * 256, row = i >> 4, c4 = i & 15;
      xr[j] = *(const float4*)&X[(size_t)(t0 + row) * DM + k0 + c4 * 4];
    }
  };
  auto loadW = [&](int k0) {
#pragma unroll
    for (int j = 0; j < 8; ++j) {
      const int s = tid + j * 256, jrow = s >> 3, c8 = s & 7;
      const int wrow = ((jrow & 31) << 3) + (jrow >> 5);   // internal j -> W row
      wrg[j] = *(const short8*)&W[(size_t)wrow * DM + k0 + c8 * 8];
    }
  };

  loadX(0);
  loadW(0);

  for (int kc = 0; kc < 8; ++kc) {
#pragma unroll
    for (int j = 0; j < 4; ++j) {
      const int i = tid + j * 256, row = i >> 4, c4 = i & 15;
      *(short4v*)&Xs[row * 72 + c4 * 4] =
          (short4v){f2bf(xr[j].x), f2bf(xr[j].y), f2bf(xr[j].z), f2bf(xr[j].w)};
    }
#pragma unroll
    for (int j = 0; j < 8; ++j) {
      const int s = tid + j * 256, jrow = s >> 3, c8 = s & 7;
      *(short8*)&Wsh[jrow * 72 + c8 * 8] = wrg[j];
    }
    __syncthreads();
    if (kc < 7) {                       // prefetch next chunk while MFMAs run
      loadX((kc + 1) * 64);
      loadW((kc + 1) * 64);
    }
#pragma unroll
    for (int ks = 0; ks < 2; ++ks) {
      short8 a0 = *(const short8*)&Xs[(wr * 32 + col) * 72 + ks * 32 + quad * 8];
      short8 a1 = *(const short8*)&Xs[(wr * 32 + 16 + col) * 72 + ks * 32 + quad * 8];
#pragma unroll
      for (int nj = 0; nj < 8; ++nj) {
        short8 b = *(const short8*)&Wsh[(wc * 128 + nj * 16 + col) * 72 + ks * 32 + quad * 8];
        acc[0][nj] = __builtin_amdgcn_mfma_f32_16x16x32_bf16(a0, b, acc[0][nj], 0, 0, 0);
        acc[1][nj] = __builtin_amdgcn_mfma_f32_16x16x32_bf16(a1, b, acc[1][nj], 0, 0, 0);
      }
    }
    __syncthreads();
  }

  // ---- epilogue: bias (+C1 for Q), LDS transpose, coalesced 16B stores ----
  short* Ct = smem;
  const int n = t0 >> 11, llb = t0 & (Ln - 1);

  if (mat < 2) {
    // Ct[t][j], pitch 268 (134 dwords == 6 mod 32: write phase conflict-free)
#pragma unroll
    for (int ri = 0; ri < 2; ++ri) {
#pragma unroll
      for (int nj = 0; nj < 8; ++nj) {
        const int j = wc * 128 + nj * 16 + col;
        const int c = ((j & 31) << 3) + (j >> 5);
        const float bi = bias[c];
#pragma unroll
        for (int r = 0; r < 4; ++r) {
          float pv = acc[ri][nj][r] + bi;
          if (mat == 0) pv *= C1;
          Ct[(wr * 32 + ri * 16 + quad * 4 + r) * 268 + j] = f2bf(pv);
        }
      }
    }
    __syncthreads();
    // 2048 chunks: id = h*256 + tok*4 + o ; per head a 4KB contiguous run
#pragma unroll
    for (int it = 0; it < 8; ++it) {
      const int cid = tid + it * 256;
      const int h = cid >> 8, tok = (cid >> 2) & 63, o = cid & 3;
      short8 val = *(const short8*)&Ct[tok * 268 + h * 32 + o * 8];
      *(short8*)&outp[((size_t)(n * NH + h) * Ln + llb + tok) * DKv + o * 8] = val;
    }
  } else {
    // CtV[j][t], pitch 72 (lane's 4 r-values are consecutive tokens -> b64 write)
#pragma unroll
    for (int ri = 0; ri < 2; ++ri) {
#pragma unroll
      for (int nj = 0; nj < 8; ++nj) {
        const int j = wc * 128 + nj * 16 + col;
        const int c = ((j & 31) << 3) + (j >> 5);
        const float bi = bias[c];
        short4v pk = (short4v){f2bf(acc[ri][nj][0] + bi), f2bf(acc[ri][nj][1] + bi),
                               f2bf(acc[ri][nj][2] + bi), f2bf(acc[ri][nj][3] + bi)};
        *(short4v*)&Ct[j * 72 + wr * 32 + ri * 16 + quad * 4] = pk;
      }
    }
    __syncthreads();
    // 2048 chunks: id = j*8 + to ; per (h,d): full 128B output line
#pragma unroll
    for (int it = 0; it < 8; ++it) {
      const int cid = tid + it * 256;
      const int j = cid >> 3, to = cid & 7;
      const int h = j >> 5, d = j & 31;
      short8 val = *(const short8*)&Ct[j * 72 + to * 8];
      *(short8*)&outp[((size_t)(n * NH + h) * DKv + d) * Ln + llb + to * 8] = val;
    }
  }
}

// ---------------- Attention: 32x32 MFMA register-P flash ----------------
// grid (Ln/128, Bn*NH) remapped so each head's 16 q-blocks share vid%8 -> one XCD
// owns each head and its 256KB K/V panel stays L2-resident (4 heads = 1MB/XCD).
// block 256 = 4 waves, 32 q per wave (q = lane&31).
// St (32key x 32q) = K·Q^T via 2x mfma_32x32x16; K staged with bit2<->bit3 key
// permutation per 32-group so St C-regs 0..7 / 8..15 are exactly the B-frags of the
// PV MFMAs. P stays in registers; O^T = V^T·P and l = ones^T·P via mfma_32x32x16.
// 128-key chunks, LDS double-buffered, one barrier per chunk.
__global__ __launch_bounds__(256) void attn_kernel(const short* __restrict__ ws,
                                                   short* __restrict__ O2b)
{
  // bijective XCD swizzle: vid%8 == xcd; head = xcd*4 + (vid>>3)>>4
  const int vid = blockIdx.x + 16 * blockIdx.y;
  const int xcd = vid & 7, jj = vid >> 3;
  const int bh = xcd * 4 + (jj >> 4);
  const int qblk = jj & 15;

  const int n = bh >> 3, h = bh & 7;
  const int tid = threadIdx.x;
  const int lane = tid & 63;
  const int col = lane & 31;        // q (and m) index
  const int hf = lane >> 5;         // lane half: k-slot group
  const int w = tid >> 6;
  const int qi = qblk * 128 + w * 32 + col;   // this lane's q row

  const short* Qh = ws;
  const short* Kg = ws + HEAD_ELEMS + (size_t)bh * Ln * DKv;      // [l][d]
  const short* Vg = ws + 2 * HEAD_ELEMS + (size_t)bh * DKv * Ln;  // [d][l]

  __shared__ short Ks[2][128 * 40];   // [perm key][d], pitch 40
  __shared__ short Vs[2][32 * 136];   // [d][key natural], pitch 136

  // Q as B-frags (pre-scaled by C1): B[k=d=c*16+8*hf+j][n=q=col]
  short8 aq[2];
#pragma unroll
  for (int c = 0; c < 2; ++c)
    aq[c] = *(const short8*)&Qh[(size_t)bh * Ln * DKv + (size_t)qi * DKv + c * 16 + hf * 8];

  short8 ones;
#pragma unroll
  for (int j = 0; j < 8; ++j) ones[j] = (short)0x3F80;  // bf16 1.0

  floatx16 o, ol;
#pragma unroll
  for (int i = 0; i < 16; ++i) { o[i] = 0.f; ol[i] = 0.f; }

  // K staging: thread (kg,khalf); LDS row = kg with bits 2,3 swapped (32-group perm)
  const int kg = tid >> 1, khalf = tid & 1;
  const int krow = (kg & ~12) | ((kg & 4) << 1) | ((kg & 8) >> 1);
  const int kst = krow * 40 + khalf * 16;
  // V staging: thread (vd, vkb) -> natural order
  const int vd = tid >> 3, vkb = tid & 7;
  const int vst = vd * 136 + vkb * 16;

  short8 kr0 = *(const short8*)(Kg + kg * 32 + khalf * 16);
  short8 kr1 = *(const short8*)(Kg + kg * 32 + khalf * 16 + 8);
  short8 vr0 = *(const short8*)(Vg + (size_t)vd * Ln + vkb * 16);
  short8 vr1 = *(const short8*)(Vg + (size_t)vd * Ln + vkb * 16 + 8);

  for (int kt = 0; kt < 16; ++kt) {
    short* ksb = Ks[kt & 1];
    short* vsb = Vs[kt & 1];
    *(short8*)&ksb[kst] = kr0;
    *(short8*)&ksb[kst + 8] = kr1;
    *(short8*)&vsb[vst] = vr0;
    *(short8*)&vsb[vst + 8] = vr1;
    __syncthreads();
    if (kt < 15) {                      // register prefetch of next 128-key chunk
      kr0 = *(const short8*)(Kg + (size_t)(kt + 1) * 4096 + kg * 32 + khalf * 16);
      kr1 = *(const short8*)(Kg + (size_t)(kt + 1) * 4096 + kg * 32 + khalf * 16 + 8);
      vr0 = *(const short8*)(Vg + (size_t)vd * Ln + (kt + 1) * 128 + vkb * 16);
      vr1 = *(const short8*)(Vg + (size_t)vd * Ln + (kt + 1) * 128 + vkb * 16 + 8);
    }

#pragma unroll
    for (int cc = 0; cc < 4; ++cc) {    // 32-key sub-chunks
      // St = K·Q^T  (A rows = permuted-key LDS rows; contraction over d=32)
      floatx16 st;
#pragma unroll
      for (int i = 0; i < 16; ++i) st[i] = 0.f;
      short8 kf0 = *(const short8*)&ksb[(cc * 32 + col) * 40 + hf * 8];
      short8 kf1 = *(const short8*)&ksb[(cc * 32 + col) * 40 + 16 + hf * 8];
      st = __builtin_amdgcn_mfma_f32_32x32x16_bf16(kf0, aq[0], st, 0, 0, 0);
      st = __builtin_amdgcn_mfma_f32_32x32x16_bf16(kf1, aq[1], st, 0, 0, 0);

      // p = exp2(st) (already log2-scaled); pack regs 0..7 / 8..15 -> B-frags
      float p[16];
#pragma unroll
      for (int i = 0; i < 16; ++i) p[i] = __builtin_amdgcn_exp2f(st[i]);
      short8 pf[2];
#pragma unroll
      for (int half = 0; half < 2; ++half) {
        unsigned u0 = __builtin_amdgcn_perm(
            __builtin_bit_cast(unsigned, p[half * 8 + 1]),
            __builtin_bit_cast(unsigned, p[half * 8 + 0]), 0x07060302u);
        unsigned u1 = __builtin_amdgcn_perm(
            __builtin_bit_cast(unsigned, p[half * 8 + 3]),
            __builtin_bit_cast(unsigned, p[half * 8 + 2]), 0x07060302u);
        unsigned u2 = __builtin_amdgcn_perm(
            __builtin_bit_cast(unsigned, p[half * 8 + 5]),
            __builtin_bit_cast(unsigned, p[half * 8 + 4]), 0x07060302u);
        unsigned u3 = __builtin_amdgcn_perm(
            __builtin_bit_cast(unsigned, p[half * 8 + 7]),
            __builtin_bit_cast(unsigned, p[half * 8 + 6]), 0x07060302u);
        uint4 uu = make_uint4(u0, u1, u2, u3);
        pf[half] = __builtin_bit_cast(short8, uu);
      }

      // l += ones^T · P   (all D rows identical = row-sum per q)
      ol = __builtin_amdgcn_mfma_f32_32x32x16_bf16(ones, pf[0], ol, 0, 0, 0);
      ol = __builtin_amdgcn_mfma_f32_32x32x16_bf16(ones, pf[1], ol, 0, 0, 0);

      // O^T += V^T · P  (A = V natural order: keys cc*32 + 16*half + 8*hf + j)
      short8 va0 = *(const short8*)&vsb[col * 136 + cc * 32 + hf * 8];
      short8 va1 = *(const short8*)&vsb[col * 136 + cc * 32 + 16 + hf * 8];
      o = __builtin_amdgcn_mfma_f32_32x32x16_bf16(va0, pf[0], o, 0, 0, 0);
      o = __builtin_amdgcn_mfma_f32_32x32x16_bf16(va1, pf[1], o, 0, 0, 0);
    }
  }

  // epilogue: l = any ol reg (rows identical); normalize; write O^T
  const float inv = 1.f / ol[0];
  short* dst = &O2b[((size_t)n * Ln + qi) * INNER + h * DKv];
#pragma unroll
  for (int g4 = 0; g4 < 4; ++g4) {      // regs 4g4..4g4+3 -> d = 8*g4 + 4*hf + (0..3)
    short4v pk = (short4v){f2bf(o[g4 * 4 + 0] * inv), f2bf(o[g4 * 4 + 1] * inv),
                           f2bf(o[g4 * 4 + 2] * inv), f2bf(o[g4 * 4 + 3] * inv)};
    *(short4v*)&dst[8 * g4 + 4 * hf] = pk;
  }
}

// ---------------- Fused FC + residual + LayerNorm -> fp32 out ----------------
// grid (TTOK/16), block 256 = 4 waves. Block = 16 tokens x 512 cols; wave w owns
// cols [w*128, w*128+128). A (O2b) staged in LDS; W read as B-frags straight from
// global (Wfcb = 256KB, fully L2-resident -- don't stage what caches fit).
// x = fc + bias + resid kept in FP32 registers (no bf16 round-trip), per-token
// mean/var via shfl_xor within 16-lane groups + tiny cross-wave LDS reduce.
__global__ __launch_bounds__(256) void fcln_kernel(
    const short* __restrict__ O2b, const short* __restrict__ Wfcb,
    const float* __restrict__ bfc, const float* __restrict__ qin,
    const float* __restrict__ gamma, const float* __restrict__ beta,
    float* __restrict__ outp)
{
  const int t0 = blockIdx.x * 16;
  const int tid = threadIdx.x;
  const int col = tid & 15;
  const int quad = (tid & 63) >> 4;
  const int w = tid >> 6;

  __shared__ short As[16 * 264];
  __shared__ float sred[2][16][4];

  {
    const int row = tid >> 4, k16 = tid & 15;        // 16 rows x 16 shorts/thread
    *(short8*)&As[row * 264 + k16 * 16] =
        *(const short8*)&O2b[(size_t)(t0 + row) * INNER + k16 * 16];
    *(short8*)&As[row * 264 + k16 * 16 + 8] =
        *(const short8*)&O2b[(size_t)(t0 + row) * INNER + k16 * 16 + 8];
  }
  __syncthreads();

  const short* Wp = Wfcb + (size_t)(w * 128 + col) * INNER + quad * 8;

  floatx4 acc[8];
#pragma unroll
  for (int nj = 0; nj < 8; ++nj) acc[nj] = (floatx4){0.f, 0.f, 0.f, 0.f};

#pragma unroll
  for (int ks = 0; ks < 8; ++ks) {
    short8 a = *(const short8*)&As[col * 264 + ks * 32 + quad * 8];
#pragma unroll
    for (int nj = 0; nj < 8; ++nj) {
      short8 b = *(const short8*)&Wp[(size_t)nj * 16 * INNER + ks * 32];
      acc[nj] = __builtin_amdgcn_mfma_f32_16x16x32_bf16(a, b, acc[nj], 0, 0, 0);
    }
  }

  // x = acc + bias + residual (fp32), accumulate per-token partial sums
  float s1[4], s2[4];
#pragma unroll
  for (int r = 0; r < 4; ++r) { s1[r] = 0.f; s2[r] = 0.f; }

#pragma unroll
  for (int nj = 0; nj < 8; ++nj) {
    const int c = w * 128 + nj * 16 + col;
    const float bi = bfc[c];
#pragma unroll
    for (int r = 0; r < 4; ++r) {
      const int t = t0 + quad * 4 + r;
      float x = acc[nj][r] + bi + qin[(size_t)t * DM + c];
      acc[nj][r] = x;
      s1[r] += x;
      s2[r] += x * x;
    }
  }
  // reduce across the 16 lanes of this quad group (cols of this wave)
#pragma unroll
  for (int r = 0; r < 4; ++r) {
#pragma unroll
    for (int off = 1; off <= 8; off <<= 1) {
      s1[r] += __shfl_xor(s1[r], off);
      s2[r] += __shfl_xor(s2[r], off);
    }
  }
  if (col == 0) {
#pragma unroll
    for (int r = 0; r < 4; ++r) {
      sred[0][quad * 4 + r][w] = s1[r];
      sred[1][quad * 4 + r][w] = s2[r];
    }
  }
  __syncthreads();

  float mean[4], rstd[4];
#pragma unroll
  for (int r = 0; r < 4; ++r) {
    const int tk = quad * 4 + r;
    const float S1 = sred[0][tk][0] + sred[0][tk][1] + sred[0][tk][2] + sred[0][tk][3];
    const float S2 = sred[1][tk][0] + sred[1][tk][1] + sred[1][tk][2] + sred[1][tk][3];
    mean[r] = S1 * (1.f / 512.f);
    const float var = S2 * (1.f / 512.f) - mean[r] * mean[r];
    rstd[r] = rsqrtf(var + 1e-5f);
  }

#pragma unroll
  for (int nj = 0; nj < 8; ++nj) {
    const int c = w * 128 + nj * 16 + col;
    const float g = gamma[c], bb = beta[c];
#pragma unroll
    for (int r = 0; r < 4; ++r) {
      const int t = t0 + quad * 4 + r;
      outp[(size_t)t * DM + c] = g * (acc[nj][r] - mean[r]) * rstd[r] + bb;
    }
  }
}

extern "C" void kernel_launch(void* const* d_in, const int* in_sizes, int n_in,
                              void* d_out, int out_size, void* d_ws, size_t ws_size,
                              hipStream_t stream) {
  const float* q     = (const float*)d_in[0];
  const float* k     = (const float*)d_in[1];
  const float* v     = (const float*)d_in[2];
  const float* Wq    = (const float*)d_in[3];
  const float* bq    = (const float*)d_in[4];
  const float* Wk    = (const float*)d_in[5];
  const float* bk    = (const float*)d_in[6];
  const float* Wv    = (const float*)d_in[7];
  const float* bv    = (const float*)d_in[8];
  const float* Wfc   = (const float*)d_in[9];
  const float* bfc   = (const float*)d_in[10];
  const float* gamma = (const float*)d_in[11];
  const float* beta  = (const float*)d_in[12];

  short* wsS  = (short*)d_ws;
  short* O2b  = wsS + 3 * HEAD_ELEMS;
  short* Wb   = wsS + WB_OFF;
  short* Wfcb = wsS + WFCB_OFF;

  cvtw_kernel<<<dim3(128, 4), 256, 0, stream>>>(Wq, Wk, Wv, Wfc, Wb, Wfcb);

  dim3 gp(TTOK / 64, 3);
  proj_kernel<<<gp, 256, 0, stream>>>(q, k, v, Wb, bq, bk, bv, wsS);

  dim3 gatt(Ln / 128, Bn * NH);
  attn_kernel<<<gatt, 256, 0, stream>>>(wsS, O2b);

  fcln_kernel<<<dim3(TTOK / 16), 256, 0, stream>>>(O2b, Wfcb, bfc, q, gamma, beta,
                                                   (float*)d_out);
}